// Round 3
// baseline (10.620 us; speedup 1.0000x reference)
//
#include <hip/hip_runtime.h>
#include <math.h>

// Problem constants (from setup_inputs): B=64, C=16, Lc=64, Ls=48, V=32000
#define NB 64
#define NC 16
#define LC 64
#define LS 48

// Fully fused, 2-barrier version: one block per batch b, 16 waves (one per
// candidate). Each wave keeps its candidate tokens in registers; after the
// score barrier EVERY wave computes the stable descending rank of its own
// candidate (16 broadcast LDS reads), so the rank-0 wave writes its tokens
// directly — no third barrier, no best-index broadcast, no LDS gather.
// Output layout (concatenated, all float32):
//   out[0 .. NB*LC)            winning candidate tokens
//   out[NB*LC .. NB*LC+NB)     out_lengths
//   out[NB*LC+NB .. +NB*NC)    sorted_scores
__global__ __launch_bounds__(NC * 64) void ngram_fused_kernel(
        const int* __restrict__ cand,
        const int* __restrict__ src,
        const int* __restrict__ pad_ptr,
        float* __restrict__ out) {
    const int b    = blockIdx.x;
    const int tid  = threadIdx.x;       // 0 .. 1023
    const int wave = tid >> 6;          // candidate index 0 .. 15
    const int lane = tid & 63;
    const int pad  = pad_ptr[0];

    __shared__ int   s_src[LS];
    __shared__ int   s_cand[NC][LC];
    __shared__ float s_sc[NC];

    if (tid < LS) s_src[tid] = src[b * LS + tid];
    const int t = cand[(b * NC + wave) * LC + lane];   // stays in a register
    s_cand[wave][lane] = t;
    __syncthreads();

    // ref norm^2 partial (identical in all waves; redundant but parallel-free)
    int rn = 0;
    if (lane < LS) {
        const int ts = s_src[lane];
        if (ts != pad) {
            #pragma unroll
            for (int j = 0; j < LS; ++j) rn += (s_src[j] == ts);
        }
    }

    // cand norm^2 and dot partials for this wave's candidate
    int cn = 0, dt = 0;
    if (t != pad) {
        #pragma unroll
        for (int j = 0; j < LC; ++j) cn += (s_cand[wave][j] == t);
        // src[j]==t implies src[j]!=pad since t!=pad
        #pragma unroll
        for (int j = 0; j < LS; ++j) dt += (s_src[j] == t);
    }

    // 64-lane reduce within the wave
    #pragma unroll
    for (int off = 32; off > 0; off >>= 1) {
        rn += __shfl_down(rn, off, 64);
        cn += __shfl_down(cn, off, 64);
        dt += __shfl_down(dt, off, 64);
    }

    float sc;
    if (lane == 0) {
        const float denom = sqrtf((float)rn) * sqrtf((float)cn);
        sc = 1.0f - (float)dt / denom;
        s_sc[wave] = sc;
    }
    __syncthreads();

    // every lane computes its wave's stable descending rank
    // (tie -> lower index first, matching stable argsort(-scores));
    // broadcast LDS reads, no bank conflicts
    const float s = s_sc[wave];
    int rank = 0;
    #pragma unroll
    for (int j = 0; j < NC; ++j) {
        const float tj = s_sc[j];
        rank += (tj > s) || (tj == s && j < wave);
    }

    if (lane == 0) out[NB * LC + NB + b * NC + rank] = s;  // sorted_scores

    if (rank == 0) {                   // exactly one wave (ranks distinct)
        out[b * LC + lane] = (float)t; // tokens straight from registers
        const unsigned long long m = __ballot(t != pad);
        if (lane == 0) out[NB * LC + b] = (float)__popcll(m);  // out_lengths
    }
}

extern "C" void kernel_launch(void* const* d_in, const int* in_sizes, int n_in,
                              void* d_out, int out_size, void* d_ws, size_t ws_size,
                              hipStream_t stream) {
    const int* cand = (const int*)d_in[0];   // [NB, NC, LC] int32
    const int* src  = (const int*)d_in[1];   // [NB, LS] int32
    // d_in[2] = vocab_size (unused: pairwise counting needs no histogram)
    const int* pad  = (const int*)d_in[3];   // pad_id

    float* out = (float*)d_out;              // 4096 + 64 + 1024 floats

    ngram_fused_kernel<<<NB, NC * 64, 0, stream>>>(cand, src, pad, out);
}